// Round 1
// baseline (13461.230 us; speedup 1.0000x reference)
//
#include <hip/hip_runtime.h>
#include <hip/hip_bf16.h>
#include <stdint.h>

// BidLSTM: B=64, T=1000, C=320, U=320.
// Phase 1: Zx[dir][t*64+b][col'] = bf16( X@W + b ), col' = u*4+gate (permuted), via MFMA GEMM.
// Phase 2: persistent kernel, 160 WGs (80/dir, 4 units each), U-slice in registers,
//          per-direction software grid barrier each step, c-state in registers.

#define Bx 64
#define Tx 1000
#define Cx 320
#define NSLICE 80

typedef __attribute__((ext_vector_type(8))) short short8;
typedef __attribute__((ext_vector_type(4))) short short4v;
typedef __attribute__((ext_vector_type(4))) float f32x4;

__device__ inline unsigned short f2bf(float f) {
  unsigned x = __builtin_bit_cast(unsigned, f);
  x += 0x7fffu + ((x >> 16) & 1u);
  return (unsigned short)(x >> 16);
}
__device__ inline float bf2f(unsigned short u) {
  unsigned x = ((unsigned)u) << 16;
  return __builtin_bit_cast(float, x);
}

// ---- ws layout (bytes) ----
#define OFF_XB   0ull                 // [64000][320] bf16 = 40,960,000
#define OFF_WT   40960000ull          // [2][1280][320] bf16 = 1,638,400
#define OFF_BP   42598400ull          // [2][1280] f32 = 10,240
#define OFF_ZX   42608640ull          // [2][64000][1280] bf16 = 327,680,000
#define OFF_HB   370288640ull         // [2buf][2dir][64][320] bf16 = 163,840
#define OFF_BAR  370452480ull         // slots[2][128] + gen, 2048 B

// Convert X [b][t][c] f32 -> Xb [(t*64+b)][c] bf16
__global__ __launch_bounds__(256) void k_prep_x(const float* __restrict__ X,
                                                unsigned short* __restrict__ Xb) {
  int i4 = blockIdx.x * 256 + threadIdx.x;
  if (i4 >= Bx * Tx * Cx / 4) return;
  int idx = i4 * 4;
  int b = idx / (Tx * Cx);
  int rem = idx - b * (Tx * Cx);
  int t = rem / Cx;
  int c = rem - t * Cx;
  float4 v = *(const float4*)(X + idx);
  short4v o;
  o[0] = (short)f2bf(v.x); o[1] = (short)f2bf(v.y);
  o[2] = (short)f2bf(v.z); o[3] = (short)f2bf(v.w);
  *(short4v*)(Xb + (size_t)(t * Bx + b) * Cx + c) = o;
}

// Wt[dir][n'][k] = bf16(W[dir][k][g*320+u]) where n' = u*4+g; biasp[dir][n'] likewise
__global__ __launch_bounds__(256) void k_prep_w(const float* __restrict__ Wf,
                                                const float* __restrict__ Wb,
                                                const float* __restrict__ bfv,
                                                const float* __restrict__ bbv,
                                                unsigned short* __restrict__ Wt,
                                                float* __restrict__ biasp) {
  int gid = blockIdx.x * 256 + threadIdx.x;
  if (gid < 2 * 1280 * 320) {
    int dir = gid / (1280 * 320);
    int rem = gid - dir * 1280 * 320;
    int n = rem / 320;
    int k = rem - n * 320;
    int u = n >> 2, g = n & 3;
    const float* W = dir ? Wb : Wf;
    Wt[gid] = f2bf(W[k * 1280 + g * 320 + u]);
  }
  if (gid < 2 * 1280) {
    int dir = gid / 1280, n = gid - dir * 1280;
    int u = n >> 2, g = n & 3;
    const float* bsrc = dir ? bbv : bfv;
    biasp[gid] = bsrc[g * 320 + u];
  }
}

// C[m][n] = sum_k A[m][k] * Bt[n][k] + bias[n], bf16 out. 128x128 tile, BK=64.
__global__ __launch_bounds__(256) void k_gemm(const unsigned short* __restrict__ A,
                                              const unsigned short* __restrict__ Bt,
                                              const float* __restrict__ biasp,
                                              unsigned short* __restrict__ Czx) {
  int bid = blockIdx.x;
  int dir = bid / 5000;
  int r = bid - dir * 5000;
  int tm = r / 10, tn = r - (r / 10) * 10;
  long m0 = (long)tm * 128;
  int n0 = tn * 128;
  const unsigned short* Bd = Bt + (size_t)dir * 1280 * 320;
  const float* bias = biasp + dir * 1280;
  unsigned short* C = Czx + (size_t)dir * 64000 * 1280;

  __shared__ __align__(16) unsigned short As[128 * 64];
  __shared__ __align__(16) unsigned short Bs[128 * 64];

  int tid = threadIdx.x;
  int wave = tid >> 6, lane = tid & 63;
  int l15 = lane & 15, l4 = lane >> 4;

  f32x4 acc[2][8];
#pragma unroll
  for (int i = 0; i < 2; i++)
#pragma unroll
    for (int j = 0; j < 8; j++) acc[i][j] = (f32x4){0.f, 0.f, 0.f, 0.f};

  for (int k0 = 0; k0 < 320; k0 += 64) {
    __syncthreads();
#pragma unroll
    for (int it = 0; it < 4; it++) {
      int idx = it * 256 + tid;
      int rr = idx >> 3, cc = idx & 7;
      const unsigned short* ga = A + (size_t)(m0 + rr) * 320 + k0 + cc * 8;
      unsigned short* la = As + (size_t)(it * 256 + wave * 64) * 8;
      __builtin_amdgcn_global_load_lds(
          (const __attribute__((address_space(1))) void*)ga,
          (__attribute__((address_space(3))) void*)la, 16, 0, 0);
      const unsigned short* gb = Bd + (size_t)(n0 + rr) * 320 + k0 + cc * 8;
      unsigned short* lb = Bs + (size_t)(it * 256 + wave * 64) * 8;
      __builtin_amdgcn_global_load_lds(
          (const __attribute__((address_space(1))) void*)gb,
          (__attribute__((address_space(3))) void*)lb, 16, 0, 0);
    }
    __syncthreads();
#pragma unroll
    for (int kk = 0; kk < 2; kk++) {
      short8 af[2], bf8[8];
#pragma unroll
      for (int mf = 0; mf < 2; mf++)
        af[mf] = *(const short8*)(As + (wave * 32 + mf * 16 + l15) * 64 + kk * 32 + l4 * 8);
#pragma unroll
      for (int nf = 0; nf < 8; nf++)
        bf8[nf] = *(const short8*)(Bs + (nf * 16 + l15) * 64 + kk * 32 + l4 * 8);
#pragma unroll
      for (int mf = 0; mf < 2; mf++)
#pragma unroll
        for (int nf = 0; nf < 8; nf++)
          acc[mf][nf] = __builtin_amdgcn_mfma_f32_16x16x32_bf16(af[mf], bf8[nf], acc[mf][nf], 0, 0, 0);
    }
  }
#pragma unroll
  for (int mf = 0; mf < 2; mf++) {
#pragma unroll
    for (int nf = 0; nf < 8; nf++) {
      int col = n0 + nf * 16 + l15;
      float bv = bias[col];
#pragma unroll
      for (int i = 0; i < 4; i++) {
        long row = m0 + wave * 32 + mf * 16 + l4 * 4 + i;
        C[(size_t)row * 1280 + col] = f2bf(acc[mf][nf][i] + bv);
      }
    }
  }
}

// Persistent recurrent kernel. 160 WGs x 256 threads. WG = (dir, 4-unit slice).
__global__ __launch_bounds__(256) void k_lstm(const unsigned short* __restrict__ Zx,
                                              const float* __restrict__ Uf,
                                              const float* __restrict__ Ub,
                                              const void* __restrict__ maskp,
                                              unsigned short* __restrict__ hbuf,
                                              float* __restrict__ out,
                                              unsigned* __restrict__ bar) {
  const int w = blockIdx.x;
  const int dir = w / NSLICE;
  const int slice = w - dir * NSLICE;
  const int u0 = slice * 4;
  const int tid = threadIdx.x;
  const int wave = tid >> 6, lane = tid & 63;
  const int l15 = lane & 15, l4 = lane >> 4;

  // mask dtype detection (bytes vs int32); t<4 is always unmasked since seq_len>=500
  const unsigned* mw = (const unsigned*)maskp;
  const bool mbyte = (mw[0] == 0x01010101u);
  const unsigned char* m8 = (const unsigned char*)maskp;
  const int* m32 = (const int*)maskp;

  // Load U slice as MFMA B-fragments into registers (resident across all steps).
  const float* U = dir ? Ub : Uf;
  const int uB = l15 >> 2, gB = l15 & 3;
  const int colU = gB * 320 + u0 + uB;
  const int kbase = l4 * 8;
  short8 bfrag[10];
#pragma unroll
  for (int kt = 0; kt < 10; kt++) {
    short8 v;
#pragma unroll
    for (int j = 0; j < 8; j++)
      v[j] = (short)f2bf(U[(size_t)(kt * 32 + kbase + j) * 1280 + colU]);
    bfrag[kt] = v;
  }

  // pointwise mapping: thread = (batch row, unit-within-slice)
  const int pb = tid >> 2;
  const int puid = tid & 3;
  const int pu = u0 + puid;
  float c_reg = 0.f, h_carry = 0.f;

  const int arow = wave * 16 + l15;  // batch row for A-fragment

  __shared__ float zsh[64][16];

  unsigned* slots = bar + dir * 128;
  unsigned* genp = bar + 256 + dir * 16;

  const size_t zx_dir = (size_t)dir * 64000 * 1280;

  for (int s = 0; s < 1000; ++s) {
    const int t = dir ? (999 - s) : s;
    const unsigned short* hr = hbuf + (((s & 1) * 2 + dir) * 64 * 320);
    unsigned short* hw = hbuf + ((((s + 1) & 1) * 2 + dir) * 64 * 320);

    // per-thread Zx (4 gates, 8B) + mask
    short4v zv = *(const short4v*)(Zx + zx_dir + (size_t)(t * 64 + pb) * 1280 + pu * 4);
    int mv = mbyte ? (int)m8[pb * 1000 + t] : m32[pb * 1000 + t];

    // z_rec = h @ U_slice via MFMA (wave m covers batch rows 16m..16m+15)
    short8 afr[10];
    const unsigned short* hp = hr + arow * 320 + kbase;
#pragma unroll
    for (int kt = 0; kt < 10; kt++) afr[kt] = *(const short8*)(hp + kt * 32);
    f32x4 acc = {0.f, 0.f, 0.f, 0.f};
#pragma unroll
    for (int kt = 0; kt < 10; kt++)
      acc = __builtin_amdgcn_mfma_f32_16x16x32_bf16(afr[kt], bfrag[kt], acc, 0, 0, 0);

    const int rr = wave * 16 + l4 * 4;
    zsh[rr + 0][l15] = acc[0];
    zsh[rr + 1][l15] = acc[1];
    zsh[rr + 2][l15] = acc[2];
    zsh[rr + 3][l15] = acc[3];
    __syncthreads();

    float zi = bf2f((unsigned short)zv[0]) + zsh[pb][puid * 4 + 0];
    float zf = bf2f((unsigned short)zv[1]) + zsh[pb][puid * 4 + 1];
    float zg = bf2f((unsigned short)zv[2]) + zsh[pb][puid * 4 + 2];
    float zo = bf2f((unsigned short)zv[3]) + zsh[pb][puid * 4 + 3];
    float ig = 1.f / (1.f + __expf(-zi));
    float fg = 1.f / (1.f + __expf(-zf));
    float gg = 2.f / (1.f + __expf(-2.f * zg)) - 1.f;
    float og = 1.f / (1.f + __expf(-zo));
    float cn = fg * c_reg + ig * gg;
    float hn = og * (2.f / (1.f + __expf(-2.f * cn)) - 1.f);
    if (mv) { c_reg = cn; h_carry = hn; }

    // h exchange: agent-scope store (write-through past non-coherent L2s)
    __hip_atomic_store(&hw[pb * 320 + pu], f2bf(h_carry), __ATOMIC_RELAXED,
                       __HIP_MEMORY_SCOPE_AGENT);
    out[(size_t)(pb * 1000 + t) * 640 + dir * 320 + pu] = h_carry;
    if (s == 999) {
      out[40960000ull + (size_t)pb * 640 + dir * 320 + pu] = h_carry;
      break;  // uniform across all WGs
    }

    // ---- per-direction grid barrier ----
    __syncthreads();  // drains each thread's stores (vmcnt) before arrival
    if (tid == 0)
      __hip_atomic_store(&slots[slice], (unsigned)(s + 1), __ATOMIC_RELEASE,
                         __HIP_MEMORY_SCOPE_AGENT);
    if (slice == 0) {
      if (tid < NSLICE) {
        while (__hip_atomic_load(&slots[tid], __ATOMIC_RELAXED,
                                 __HIP_MEMORY_SCOPE_AGENT) < (unsigned)(s + 1))
          __builtin_amdgcn_s_sleep(1);
      }
      __syncthreads();
      if (tid == 0)
        __hip_atomic_store(genp, (unsigned)(s + 1), __ATOMIC_RELEASE,
                           __HIP_MEMORY_SCOPE_AGENT);
    } else {
      if (tid == 0) {
        while (__hip_atomic_load(genp, __ATOMIC_RELAXED,
                                 __HIP_MEMORY_SCOPE_AGENT) < (unsigned)(s + 1))
          __builtin_amdgcn_s_sleep(1);
      }
      __syncthreads();
    }
    __builtin_amdgcn_fence(__ATOMIC_ACQUIRE, "agent");  // L2 inv: see fresh h
  }
}

extern "C" void kernel_launch(void* const* d_in, const int* in_sizes, int n_in,
                              void* d_out, int out_size, void* d_ws, size_t ws_size,
                              hipStream_t stream) {
  const float* X = (const float*)d_in[0];
  const void* Mk = d_in[1];
  const float* Wf = (const float*)d_in[2];
  const float* Uf = (const float*)d_in[3];
  const float* bfv = (const float*)d_in[4];
  const float* Wb = (const float*)d_in[5];
  const float* Ub = (const float*)d_in[6];
  const float* bbv = (const float*)d_in[7];

  char* ws = (char*)d_ws;
  unsigned short* Xb = (unsigned short*)(ws + OFF_XB);
  unsigned short* Wt = (unsigned short*)(ws + OFF_WT);
  float* bp = (float*)(ws + OFF_BP);
  unsigned short* Zx = (unsigned short*)(ws + OFF_ZX);
  unsigned short* hbuf = (unsigned short*)(ws + OFF_HB);
  unsigned* bar = (unsigned*)(ws + OFF_BAR);

  k_prep_x<<<dim3(20000), dim3(256), 0, stream>>>(X, Xb);
  k_prep_w<<<dim3(3200), dim3(256), 0, stream>>>(Wf, Wb, bfv, bbv, Wt, bp);
  hipMemsetAsync(ws + OFF_HB, 0, 163840 + 2048, stream);
  k_gemm<<<dim3(10000), dim3(256), 0, stream>>>(Xb, Wt, bp, Zx);
  k_lstm<<<dim3(160), dim3(256), 0, stream>>>(Zx, Uf, Ub, Mk, hbuf, (float*)d_out, bar);
}

// Round 2
// 6358.232 us; speedup vs baseline: 2.1171x; 2.1171x over previous
//
#include <hip/hip_runtime.h>
#include <hip/hip_bf16.h>
#include <stdint.h>

// BidLSTM: B=64, T=1000, C=320, U=320.
// Phase 1: Zx2[dir][slice][t][b][32] = bf16(X@W + b), slice = unit-octet, via MFMA GEMM.
// Phase 2: persistent kernel, 80 WGs (40/dir, 8 units each), U-slice in registers,
//          single-hop per-direction barrier, L2-bypass h exchange (no buffer_inv),
//          out stores off the critical path.

#define Bx 64
#define Tx 1000
#define Cx 320
#define NSLICE 40   // WGs per direction
#define UPW 8       // units per WG

typedef __attribute__((ext_vector_type(8))) short short8;
typedef __attribute__((ext_vector_type(4))) short short4v;
typedef __attribute__((ext_vector_type(4))) float f32x4;

__device__ inline unsigned short f2bf(float f) {
  unsigned x = __builtin_bit_cast(unsigned, f);
  x += 0x7fffu + ((x >> 16) & 1u);
  return (unsigned short)(x >> 16);
}
__device__ inline float bf2f(unsigned short u) {
  unsigned x = ((unsigned)u) << 16;
  return __builtin_bit_cast(float, x);
}

// ---- ws layout (bytes) ----
// Xb region [0, 40.96 MB) is dead after k_gemm; mask2/bar/hbuf overlay it.
#define OFF_MB   0ull                 // mask2 [1000] u64 = 8,000
#define OFF_BAR  8192ull              // slots [2][40] stride-16 u32 = 5,120
#define OFF_HB   16384ull             // hbuf [2buf][2dir][64][320] bf16 = 163,840
#define OFF_XB   0ull                 // Xb [64000][320] bf16 = 40,960,000 (pre-GEMM only)
#define OFF_WT   40960000ull          // Wt [2][1280][320] bf16 = 1,638,400
#define OFF_BP   42598400ull          // bias [2][1280] f32 = 10,240
#define OFF_ZX   42608640ull          // Zx2 [2][40][1000][2048] bf16 = 327,680,000
// total = 370,288,640 <= round-1 footprint (proven to fit)

// Convert X [b][t][c] f32 -> Xb [(t*64+b)][c] bf16
__global__ __launch_bounds__(256) void k_prep_x(const float* __restrict__ X,
                                                unsigned short* __restrict__ Xb) {
  int i4 = blockIdx.x * 256 + threadIdx.x;
  if (i4 >= Bx * Tx * Cx / 4) return;
  int idx = i4 * 4;
  int b = idx / (Tx * Cx);
  int rem = idx - b * (Tx * Cx);
  int t = rem / Cx;
  int c = rem - t * Cx;
  float4 v = *(const float4*)(X + idx);
  short4v o;
  o[0] = (short)f2bf(v.x); o[1] = (short)f2bf(v.y);
  o[2] = (short)f2bf(v.z); o[3] = (short)f2bf(v.w);
  *(short4v*)(Xb + (size_t)(t * Bx + b) * Cx + c) = o;
}

// Wt[dir][n'][k] = bf16(W[dir][k][g*320+u]) where n' = u*4+g; biasp[dir][n'] likewise
__global__ __launch_bounds__(256) void k_prep_w(const float* __restrict__ Wf,
                                                const float* __restrict__ Wb,
                                                const float* __restrict__ bfv,
                                                const float* __restrict__ bbv,
                                                unsigned short* __restrict__ Wt,
                                                float* __restrict__ biasp) {
  int gid = blockIdx.x * 256 + threadIdx.x;
  if (gid < 2 * 1280 * 320) {
    int dir = gid / (1280 * 320);
    int rem = gid - dir * 1280 * 320;
    int n = rem / 320;
    int k = rem - n * 320;
    int u = n >> 2, g = n & 3;
    const float* W = dir ? Wb : Wf;
    Wt[gid] = f2bf(W[k * 1280 + g * 320 + u]);
  }
  if (gid < 2 * 1280) {
    int dir = gid / 1280, n = gid - dir * 1280;
    int u = n >> 2, g = n & 3;
    const float* bsrc = dir ? bbv : bfv;
    biasp[gid] = bsrc[g * 320 + u];
  }
}

// mask2[t] = bitmask over batches (bit b = mask[b][t]); detects byte vs int32 mask.
__global__ __launch_bounds__(256) void k_prep_mask(const void* __restrict__ maskp,
                                                   unsigned long long* __restrict__ mask2) {
  int t = blockIdx.x * 256 + threadIdx.x;
  if (t >= Tx) return;
  const unsigned* mw = (const unsigned*)maskp;
  const bool mbyte = (mw[0] == 0x01010101u);
  unsigned long long wv = 0ull;
  if (mbyte) {
    const unsigned char* m8 = (const unsigned char*)maskp;
#pragma unroll 8
    for (int b = 0; b < Bx; b++)
      wv |= (unsigned long long)(m8[b * Tx + t] & 1) << b;
  } else {
    const int* m32 = (const int*)maskp;
#pragma unroll 8
    for (int b = 0; b < Bx; b++)
      wv |= (unsigned long long)(m32[b * Tx + t] & 1) << b;
  }
  mask2[t] = wv;
}

// C = A @ Bt^T + bias, written to Zx2[dir][slice][t][b][32]. 128x128 tile, BK=64.
__global__ __launch_bounds__(256) void k_gemm(const unsigned short* __restrict__ A,
                                              const unsigned short* __restrict__ Bt,
                                              const float* __restrict__ biasp,
                                              unsigned short* __restrict__ Czx) {
  int bid = blockIdx.x;
  int dir = bid / 5000;
  int r = bid - dir * 5000;
  int tm = r / 10, tn = r - (r / 10) * 10;
  long m0 = (long)tm * 128;
  int n0 = tn * 128;
  const unsigned short* Bd = Bt + (size_t)dir * 1280 * 320;
  const float* bias = biasp + dir * 1280;

  __shared__ __align__(16) unsigned short As[128 * 64];
  __shared__ __align__(16) unsigned short Bs[128 * 64];

  int tid = threadIdx.x;
  int wave = tid >> 6, lane = tid & 63;
  int l15 = lane & 15, l4 = lane >> 4;

  f32x4 acc[2][8];
#pragma unroll
  for (int i = 0; i < 2; i++)
#pragma unroll
    for (int j = 0; j < 8; j++) acc[i][j] = (f32x4){0.f, 0.f, 0.f, 0.f};

  for (int k0 = 0; k0 < 320; k0 += 64) {
    __syncthreads();
#pragma unroll
    for (int it = 0; it < 4; it++) {
      int idx = it * 256 + tid;
      int rr = idx >> 3, cc = idx & 7;
      const unsigned short* ga = A + (size_t)(m0 + rr) * 320 + k0 + cc * 8;
      unsigned short* la = As + (size_t)(it * 256 + wave * 64) * 8;
      __builtin_amdgcn_global_load_lds(
          (const __attribute__((address_space(1))) void*)ga,
          (__attribute__((address_space(3))) void*)la, 16, 0, 0);
      const unsigned short* gb = Bd + (size_t)(n0 + rr) * 320 + k0 + cc * 8;
      unsigned short* lb = Bs + (size_t)(it * 256 + wave * 64) * 8;
      __builtin_amdgcn_global_load_lds(
          (const __attribute__((address_space(1))) void*)gb,
          (__attribute__((address_space(3))) void*)lb, 16, 0, 0);
    }
    __syncthreads();
#pragma unroll
    for (int kk = 0; kk < 2; kk++) {
      short8 af[2], bf8[8];
#pragma unroll
      for (int mf = 0; mf < 2; mf++)
        af[mf] = *(const short8*)(As + (wave * 32 + mf * 16 + l15) * 64 + kk * 32 + l4 * 8);
#pragma unroll
      for (int nf = 0; nf < 8; nf++)
        bf8[nf] = *(const short8*)(Bs + (nf * 16 + l15) * 64 + kk * 32 + l4 * 8);
#pragma unroll
      for (int mf = 0; mf < 2; mf++)
#pragma unroll
        for (int nf = 0; nf < 8; nf++)
          acc[mf][nf] = __builtin_amdgcn_mfma_f32_16x16x32_bf16(af[mf], bf8[nf], acc[mf][nf], 0, 0, 0);
    }
  }
  // epilogue: Zx2 element = ((dir*40+slice)*1000 + t)*2048 + b*32 + i32
#pragma unroll
  for (int mf = 0; mf < 2; mf++) {
#pragma unroll
    for (int nf = 0; nf < 8; nf++) {
      int col = n0 + nf * 16 + l15;
      float bv = bias[col];
      int slice = col >> 5, i32v = col & 31;
      size_t sbase = ((size_t)(dir * NSLICE + slice)) * Tx * 2048;
#pragma unroll
      for (int i = 0; i < 4; i++) {
        long m = m0 + wave * 32 + mf * 16 + l4 * 4 + i;
        long t = m >> 6;
        int b = (int)(m & 63);
        Czx[sbase + (size_t)t * 2048 + b * 32 + i32v] = f2bf(acc[mf][nf][i] + bv);
      }
    }
  }
}

// Persistent recurrent kernel. 80 WGs x 256 threads. WG = (dir, 8-unit slice).
__global__ __launch_bounds__(256, 1) void k_lstm(const unsigned short* __restrict__ Zx,
                                                 const float* __restrict__ Uf,
                                                 const float* __restrict__ Ub,
                                                 const unsigned long long* __restrict__ mask2,
                                                 unsigned short* __restrict__ hbuf,
                                                 float* __restrict__ out,
                                                 unsigned* __restrict__ bar) {
  const int w = blockIdx.x;
  const int dir = w / NSLICE;
  const int slice = w - dir * NSLICE;
  const int u0 = slice * UPW;
  const int tid = threadIdx.x;
  const int wave = tid >> 6, lane = tid & 63;
  const int l15 = lane & 15, l4 = lane >> 4;

  // U slice as MFMA B-fragments in registers, resident for all 1000 steps.
  const float* U = dir ? Ub : Uf;
  short8 bfrag[2][10];
#pragma unroll
  for (int nf = 0; nf < 2; nf++) {
    int i32v = nf * 16 + l15;
    int colU = (i32v & 3) * 320 + u0 + (i32v >> 2);
#pragma unroll
    for (int kt = 0; kt < 10; kt++) {
      short8 v;
#pragma unroll
      for (int j = 0; j < 8; j++)
        v[j] = (short)f2bf(U[(size_t)(kt * 32 + l4 * 8 + j) * 1280 + colU]);
      bfrag[nf][kt] = v;
    }
  }

  // pointwise mapping: thread = (batch pb, unit pair uu2,uu2+1)
  const int pb = tid >> 2;
  const int uu2 = (tid & 3) * 2;
  const int arow = wave * 16 + l15;  // batch row for A-fragment
  float c0 = 0.f, c1 = 0.f, h0 = 0.f, h1 = 0.f;

  __shared__ float zsh[64][32];

  unsigned* slots = bar + (size_t)dir * NSLICE * 16;
  const unsigned short* zbase = Zx + ((size_t)(dir * NSLICE + slice)) * Tx * 2048;

  // prefetch step 0
  int t = dir ? (Tx - 1) : 0;
  short8 zv = *(const short8*)(zbase + (size_t)t * 2048 + tid * 8);
  unsigned long long mwrd = mask2[t];

  for (int s = 0;; ++s) {
    t = dir ? (Tx - 1 - s) : s;
    float zr[8];
    if (s > 0) {
      // single-hop barrier: wait for all slices' step-s signal
      if (tid < NSLICE) {
        while (__hip_atomic_load(&slots[tid * 16], __ATOMIC_RELAXED,
                                 __HIP_MEMORY_SCOPE_AGENT) < (unsigned)s)
          __builtin_amdgcn_s_sleep(1);
      }
      __syncthreads();  // also a compiler fence: h loads below can't hoist

      // h @ U_slice via MFMA; h read with L2-bypassing loads (no buffer_inv needed)
      const unsigned short* hr = hbuf + ((size_t)((s & 1) * 2 + dir)) * Bx * 320;
      const unsigned short* hp = hr + arow * 320 + l4 * 8;
      short8 afr[10];
#pragma unroll
      for (int kt = 0; kt < 10; kt++) {
        union { unsigned long long q[2]; short8 v; } u;
        u.q[0] = __hip_atomic_load((const unsigned long long*)(hp + kt * 32),
                                   __ATOMIC_RELAXED, __HIP_MEMORY_SCOPE_AGENT);
        u.q[1] = __hip_atomic_load((const unsigned long long*)(hp + kt * 32 + 4),
                                   __ATOMIC_RELAXED, __HIP_MEMORY_SCOPE_AGENT);
        afr[kt] = u.v;
      }
#pragma unroll
      for (int nf = 0; nf < 2; nf++) {
        f32x4 a0 = {0.f, 0.f, 0.f, 0.f}, a1 = {0.f, 0.f, 0.f, 0.f};
#pragma unroll
        for (int k2 = 0; k2 < 5; k2++) {
          a0 = __builtin_amdgcn_mfma_f32_16x16x32_bf16(afr[2 * k2], bfrag[nf][2 * k2], a0, 0, 0, 0);
          a1 = __builtin_amdgcn_mfma_f32_16x16x32_bf16(afr[2 * k2 + 1], bfrag[nf][2 * k2 + 1], a1, 0, 0, 0);
        }
        int rr = wave * 16 + l4 * 4;
        zsh[rr + 0][nf * 16 + l15] = a0[0] + a1[0];
        zsh[rr + 1][nf * 16 + l15] = a0[1] + a1[1];
        zsh[rr + 2][nf * 16 + l15] = a0[2] + a1[2];
        zsh[rr + 3][nf * 16 + l15] = a0[3] + a1[3];
      }
      __syncthreads();
#pragma unroll
      for (int j = 0; j < 8; j++) zr[j] = zsh[pb][uu2 * 4 + j];
    } else {
#pragma unroll
      for (int j = 0; j < 8; j++) zr[j] = 0.f;
    }

    // gates for 2 units
    int mv = (int)((mwrd >> pb) & 1ull);
    {
      float zi = bf2f((unsigned short)zv[0]) + zr[0];
      float zf = bf2f((unsigned short)zv[1]) + zr[1];
      float zg = bf2f((unsigned short)zv[2]) + zr[2];
      float zo = bf2f((unsigned short)zv[3]) + zr[3];
      float ig = 1.f / (1.f + __expf(-zi));
      float fg = 1.f / (1.f + __expf(-zf));
      float gg = 2.f / (1.f + __expf(-2.f * zg)) - 1.f;
      float og = 1.f / (1.f + __expf(-zo));
      float cn = fg * c0 + ig * gg;
      float hn = og * (2.f / (1.f + __expf(-2.f * cn)) - 1.f);
      if (mv) { c0 = cn; h0 = hn; }
    }
    {
      float zi = bf2f((unsigned short)zv[4]) + zr[4];
      float zf = bf2f((unsigned short)zv[5]) + zr[5];
      float zg = bf2f((unsigned short)zv[6]) + zr[6];
      float zo = bf2f((unsigned short)zv[7]) + zr[7];
      float ig = 1.f / (1.f + __expf(-zi));
      float fg = 1.f / (1.f + __expf(-zf));
      float gg = 2.f / (1.f + __expf(-2.f * zg)) - 1.f;
      float og = 1.f / (1.f + __expf(-zo));
      float cn = fg * c1 + ig * gg;
      float hn = og * (2.f / (1.f + __expf(-2.f * cn)) - 1.f);
      if (mv) { c1 = cn; h1 = hn; }
    }

    // h exchange: write-through agent store (critical path)
    unsigned short* hw = hbuf + ((size_t)(((s + 1) & 1) * 2 + dir)) * Bx * 320;
    unsigned hv = (unsigned)f2bf(h0) | ((unsigned)f2bf(h1) << 16);
    __hip_atomic_store((unsigned*)(hw + pb * 320 + u0 + uu2), hv,
                       __ATOMIC_RELAXED, __HIP_MEMORY_SCOPE_AGENT);

    __syncthreads();  // all waves' h stores drained (vmcnt 0) before signal
    if (tid == 0 && s < Tx - 1)
      __hip_atomic_store(&slots[slice * 16], (unsigned)(s + 1), __ATOMIC_RELEASE,
                         __HIP_MEMORY_SCOPE_AGENT);

    // out stores: OFF the critical path (drained by next step's barrier round)
    *(float2*)(out + ((size_t)pb * Tx + t) * 640 + dir * 320 + u0 + uu2) =
        make_float2(h0, h1);
    if (s == Tx - 1) {
      *(float2*)(out + 40960000ull + (size_t)pb * 640 + dir * 320 + u0 + uu2) =
          make_float2(h0, h1);
      break;  // uniform
    }

    // prefetch next step's Zx slab + mask word (overlaps barrier wait)
    int tn = dir ? (Tx - 2 - s) : (s + 1);
    zv = *(const short8*)(zbase + (size_t)tn * 2048 + tid * 8);
    mwrd = mask2[tn];
  }
}

extern "C" void kernel_launch(void* const* d_in, const int* in_sizes, int n_in,
                              void* d_out, int out_size, void* d_ws, size_t ws_size,
                              hipStream_t stream) {
  const float* X = (const float*)d_in[0];
  const void* Mk = d_in[1];
  const float* Wf = (const float*)d_in[2];
  const float* Uf = (const float*)d_in[3];
  const float* bfv = (const float*)d_in[4];
  const float* Wb = (const float*)d_in[5];
  const float* Ub = (const float*)d_in[6];
  const float* bbv = (const float*)d_in[7];

  char* ws = (char*)d_ws;
  unsigned short* Xb = (unsigned short*)(ws + OFF_XB);
  unsigned short* Wt = (unsigned short*)(ws + OFF_WT);
  float* bp = (float*)(ws + OFF_BP);
  unsigned short* Zx = (unsigned short*)(ws + OFF_ZX);
  unsigned long long* mask2 = (unsigned long long*)(ws + OFF_MB);
  unsigned short* hbuf = (unsigned short*)(ws + OFF_HB);
  unsigned* bar = (unsigned*)(ws + OFF_BAR);

  k_prep_x<<<dim3(20000), dim3(256), 0, stream>>>(X, Xb);
  k_prep_w<<<dim3(3200), dim3(256), 0, stream>>>(Wf, Wb, bfv, bbv, Wt, bp);
  k_gemm<<<dim3(10000), dim3(256), 0, stream>>>(Xb, Wt, bp, Zx);
  // mask2/bar/hbuf overlay the (now dead) Xb region — initialize after k_gemm
  hipMemsetAsync(ws + OFF_BAR, 0, 5120, stream);
  k_prep_mask<<<dim3(4), dim3(256), 0, stream>>>(Mk, mask2);
  k_lstm<<<dim3(2 * NSLICE), dim3(256), 0, stream>>>(Zx, Uf, Ub, mask2, hbuf,
                                                     (float*)d_out, bar);
}

// Round 4
// 5669.064 us; speedup vs baseline: 2.3745x; 1.1216x over previous
//
#include <hip/hip_runtime.h>
#include <hip/hip_bf16.h>
#include <stdint.h>

// BidLSTM: B=64, T=1000, C=320, U=320.
// Phase 1: Zx[dir][slice][t][b][64] = bf16(X@W + b), slice = 16-unit group, via MFMA GEMM.
// Phase 2: persistent kernel, 40 WGs (20/dir, 16 units each), U-slice in registers,
//          single-hop per-direction barrier with RELEASE slot stores (replay-proven
//          round-2 protocol), sc-bypass h exchange, write-through out stores so L2
//          stays clean and the release's buffer_wbl2 is ~free.

#define Bx 64
#define Tx 1000
#define Cx 320
#define NSLICE 20   // WGs per direction
#define UPW 16      // units per WG

typedef __attribute__((ext_vector_type(8))) short short8;
typedef __attribute__((ext_vector_type(4))) short short4v;
typedef __attribute__((ext_vector_type(4))) float f32x4;

__device__ inline unsigned short f2bf(float f) {
  unsigned x = __builtin_bit_cast(unsigned, f);
  x += 0x7fffu + ((x >> 16) & 1u);
  return (unsigned short)(x >> 16);
}
__device__ inline float bf2f(unsigned short u) {
  unsigned x = ((unsigned)u) << 16;
  return __builtin_bit_cast(float, x);
}

// ---- ws layout (bytes) ----
// Xb region [0, 40.96 MB) is dead after k_gemm; mask2/bar/hbuf overlay it.
#define OFF_MB   0ull                 // mask2 [1000] u64 = 8,000
#define OFF_BAR  8192ull              // slots [2][20] stride-16 u32 = 2,560
#define OFF_HB   16384ull             // hbuf [2buf][2dir][64][320] bf16 = 163,840
#define OFF_XB   0ull                 // Xb [64000][320] bf16 = 40,960,000 (pre-GEMM only)
#define OFF_WT   40960000ull          // Wt [2][1280][320] bf16 = 1,638,400
#define OFF_BP   42598400ull          // bias [2][1280] f32 = 10,240
#define OFF_ZX   42608640ull          // Zx [2][20][1000][4096] bf16 = 327,680,000
// total = 370,288,640 (same footprint as rounds 1-3 — proven to fit)

// Convert X [b][t][c] f32 -> Xb [(t*64+b)][c] bf16
__global__ __launch_bounds__(256) void k_prep_x(const float* __restrict__ X,
                                                unsigned short* __restrict__ Xb) {
  int i4 = blockIdx.x * 256 + threadIdx.x;
  if (i4 >= Bx * Tx * Cx / 4) return;
  int idx = i4 * 4;
  int b = idx / (Tx * Cx);
  int rem = idx - b * (Tx * Cx);
  int t = rem / Cx;
  int c = rem - t * Cx;
  float4 v = *(const float4*)(X + idx);
  short4v o;
  o[0] = (short)f2bf(v.x); o[1] = (short)f2bf(v.y);
  o[2] = (short)f2bf(v.z); o[3] = (short)f2bf(v.w);
  *(short4v*)(Xb + (size_t)(t * Bx + b) * Cx + c) = o;
}

// Wt[dir][n'][k] = bf16(W[dir][k][g*320+u]) where n' = u*4+g; biasp[dir][n'] likewise
__global__ __launch_bounds__(256) void k_prep_w(const float* __restrict__ Wf,
                                                const float* __restrict__ Wb,
                                                const float* __restrict__ bfv,
                                                const float* __restrict__ bbv,
                                                unsigned short* __restrict__ Wt,
                                                float* __restrict__ biasp) {
  int gid = blockIdx.x * 256 + threadIdx.x;
  if (gid < 2 * 1280 * 320) {
    int dir = gid / (1280 * 320);
    int rem = gid - dir * 1280 * 320;
    int n = rem / 320;
    int k = rem - n * 320;
    int u = n >> 2, g = n & 3;
    const float* W = dir ? Wb : Wf;
    Wt[gid] = f2bf(W[k * 1280 + g * 320 + u]);
  }
  if (gid < 2 * 1280) {
    int dir = gid / 1280, n = gid - dir * 1280;
    int u = n >> 2, g = n & 3;
    const float* bsrc = dir ? bbv : bfv;
    biasp[gid] = bsrc[g * 320 + u];
  }
}

// mask2[t] = bitmask over batches (bit b = mask[b][t]); detects byte vs int32 mask.
__global__ __launch_bounds__(256) void k_prep_mask(const void* __restrict__ maskp,
                                                   unsigned long long* __restrict__ mask2) {
  int t = blockIdx.x * 256 + threadIdx.x;
  if (t >= Tx) return;
  const unsigned* mw = (const unsigned*)maskp;
  const bool mbyte = (mw[0] == 0x01010101u);
  unsigned long long wv = 0ull;
  if (mbyte) {
    const unsigned char* m8 = (const unsigned char*)maskp;
#pragma unroll 8
    for (int b = 0; b < Bx; b++)
      wv |= (unsigned long long)(m8[b * Tx + t] & 1) << b;
  } else {
    const int* m32 = (const int*)maskp;
#pragma unroll 8
    for (int b = 0; b < Bx; b++)
      wv |= (unsigned long long)(m32[b * Tx + t] & 1) << b;
  }
  mask2[t] = wv;
}

// C = A @ Bt^T + bias, written to Zx[dir][slice][t][b][64]. 128x128 tile, BK=64.
__global__ __launch_bounds__(256) void k_gemm(const unsigned short* __restrict__ A,
                                              const unsigned short* __restrict__ Bt,
                                              const float* __restrict__ biasp,
                                              unsigned short* __restrict__ Czx) {
  int bid = blockIdx.x;
  int dir = bid / 5000;
  int r = bid - dir * 5000;
  int tm = r / 10, tn = r - (r / 10) * 10;
  long m0 = (long)tm * 128;
  int n0 = tn * 128;
  const unsigned short* Bd = Bt + (size_t)dir * 1280 * 320;
  const float* bias = biasp + dir * 1280;

  __shared__ __align__(16) unsigned short As[128 * 64];
  __shared__ __align__(16) unsigned short Bs[128 * 64];

  int tid = threadIdx.x;
  int wave = tid >> 6, lane = tid & 63;
  int l15 = lane & 15, l4 = lane >> 4;

  f32x4 acc[2][8];
#pragma unroll
  for (int i = 0; i < 2; i++)
#pragma unroll
    for (int j = 0; j < 8; j++) acc[i][j] = (f32x4){0.f, 0.f, 0.f, 0.f};

  for (int k0 = 0; k0 < 320; k0 += 64) {
    __syncthreads();
#pragma unroll
    for (int it = 0; it < 4; it++) {
      int idx = it * 256 + tid;
      int rr = idx >> 3, cc = idx & 7;
      const unsigned short* ga = A + (size_t)(m0 + rr) * 320 + k0 + cc * 8;
      unsigned short* la = As + (size_t)(it * 256 + wave * 64) * 8;
      __builtin_amdgcn_global_load_lds(
          (const __attribute__((address_space(1))) void*)ga,
          (__attribute__((address_space(3))) void*)la, 16, 0, 0);
      const unsigned short* gb = Bd + (size_t)(n0 + rr) * 320 + k0 + cc * 8;
      unsigned short* lb = Bs + (size_t)(it * 256 + wave * 64) * 8;
      __builtin_amdgcn_global_load_lds(
          (const __attribute__((address_space(1))) void*)gb,
          (__attribute__((address_space(3))) void*)lb, 16, 0, 0);
    }
    __syncthreads();
#pragma unroll
    for (int kk = 0; kk < 2; kk++) {
      short8 af[2], bf8[8];
#pragma unroll
      for (int mf = 0; mf < 2; mf++)
        af[mf] = *(const short8*)(As + (wave * 32 + mf * 16 + l15) * 64 + kk * 32 + l4 * 8);
#pragma unroll
      for (int nf = 0; nf < 8; nf++)
        bf8[nf] = *(const short8*)(Bs + (nf * 16 + l15) * 64 + kk * 32 + l4 * 8);
#pragma unroll
      for (int mf = 0; mf < 2; mf++)
#pragma unroll
        for (int nf = 0; nf < 8; nf++)
          acc[mf][nf] = __builtin_amdgcn_mfma_f32_16x16x32_bf16(af[mf], bf8[nf], acc[mf][nf], 0, 0, 0);
    }
  }
  // epilogue: Zx element = ((dir*20+slice)*1000 + t)*4096 + b*64 + i64
#pragma unroll
  for (int mf = 0; mf < 2; mf++) {
#pragma unroll
    for (int nf = 0; nf < 8; nf++) {
      int col = n0 + nf * 16 + l15;
      float bv = bias[col];
      int slice = col >> 6, i64v = col & 63;
      size_t sbase = ((size_t)(dir * NSLICE + slice)) * Tx * 4096;
#pragma unroll
      for (int i = 0; i < 4; i++) {
        long m = m0 + wave * 32 + mf * 16 + l4 * 4 + i;
        long t = m >> 6;
        int b = (int)(m & 63);
        Czx[sbase + (size_t)t * 4096 + b * 64 + i64v] = f2bf(acc[mf][nf][i] + bv);
      }
    }
  }
}

// Persistent recurrent kernel. 40 WGs x 256 threads. WG = (dir, 16-unit slice).
__global__ __launch_bounds__(256, 1) void k_lstm(const unsigned short* __restrict__ Zx,
                                                 const float* __restrict__ Uf,
                                                 const float* __restrict__ Ub,
                                                 const unsigned long long* __restrict__ mask2,
                                                 unsigned short* __restrict__ hbuf,
                                                 float* __restrict__ out,
                                                 unsigned* __restrict__ bar) {
  const int w = blockIdx.x;
  const int dir = w / NSLICE;
  const int slice = w - dir * NSLICE;
  const int u0 = slice * UPW;
  const int tid = threadIdx.x;
  const int wave = tid >> 6, lane = tid & 63;
  const int l15 = lane & 15, l4 = lane >> 4;

  // U slice as MFMA B-fragments in registers, resident for all 1000 steps.
  const float* U = dir ? Ub : Uf;
  short8 bfrag[4][10];
#pragma unroll
  for (int nf = 0; nf < 4; nf++) {
    int ncol = nf * 16 + l15;                       // col within 64-wide slice
    int colU = (ncol & 3) * 320 + u0 + (ncol >> 2); // original U column
#pragma unroll
    for (int kt = 0; kt < 10; kt++) {
      short8 v;
#pragma unroll
      for (int j = 0; j < 8; j++)
        v[j] = (short)f2bf(U[(size_t)(kt * 32 + l4 * 8 + j) * 1280 + colU]);
      bfrag[nf][kt] = v;
    }
  }

  // pointwise mapping: thread = (batch pb, unit quad uq -> units u0+uq*4 .. +3)
  const int pb = tid >> 2;
  const int uq = tid & 3;
  const int arow = wave * 16 + l15;  // batch row for A-fragment
  float c0 = 0.f, c1 = 0.f, c2 = 0.f, c3 = 0.f;
  float h0 = 0.f, h1 = 0.f, h2 = 0.f, h3 = 0.f;

  __shared__ float zsh[64][68];  // padded: 272B row stride, 16B aligned

  unsigned* slots = bar + dir * NSLICE * 16;
  const unsigned short* zbase = Zx + ((size_t)(dir * NSLICE + slice)) * Tx * 4096;

  // prefetch step 0
  int t = dir ? (Tx - 1) : 0;
  short8 zv0 = *(const short8*)(zbase + (size_t)t * 4096 + pb * 64 + uq * 16);
  short8 zv1 = *(const short8*)(zbase + (size_t)t * 4096 + pb * 64 + uq * 16 + 8);
  unsigned long long mwrd = mask2[t];

  for (int s = 0;; ++s) {
    t = dir ? (Tx - 1 - s) : s;
    float4 zr0, zr1, zr2, zr3;
    if (s > 0) {
      // single-hop barrier: wait for all slices' step-s signal
      if (tid < NSLICE) {
        while (__hip_atomic_load(&slots[tid * 16], __ATOMIC_RELAXED,
                                 __HIP_MEMORY_SCOPE_AGENT) < (unsigned)s)
          __builtin_amdgcn_s_sleep(1);
      }
      __syncthreads();  // compiler fence; in-order issue keeps h loads after

      // h @ U_slice via MFMA; h read with sc-bypass loads (no buffer_inv)
      const unsigned short* hr = hbuf + ((size_t)((s & 1) * 2 + dir)) * Bx * 320;
      const unsigned short* hp = hr + arow * 320 + l4 * 8;
      short8 afr[10];
#pragma unroll
      for (int kt = 0; kt < 10; kt++) {
        union { unsigned long long q[2]; short8 v; } u;
        u.q[0] = __hip_atomic_load((const unsigned long long*)(hp + kt * 32),
                                   __ATOMIC_RELAXED, __HIP_MEMORY_SCOPE_AGENT);
        u.q[1] = __hip_atomic_load((const unsigned long long*)(hp + kt * 32 + 4),
                                   __ATOMIC_RELAXED, __HIP_MEMORY_SCOPE_AGENT);
        afr[kt] = u.v;
      }
#pragma unroll
      for (int nf = 0; nf < 4; nf++) {
        f32x4 a0 = {0.f, 0.f, 0.f, 0.f}, a1 = {0.f, 0.f, 0.f, 0.f};
#pragma unroll
        for (int k2 = 0; k2 < 5; k2++) {
          a0 = __builtin_amdgcn_mfma_f32_16x16x32_bf16(afr[2 * k2], bfrag[nf][2 * k2], a0, 0, 0, 0);
          a1 = __builtin_amdgcn_mfma_f32_16x16x32_bf16(afr[2 * k2 + 1], bfrag[nf][2 * k2 + 1], a1, 0, 0, 0);
        }
        int rr = wave * 16 + l4 * 4;
        zsh[rr + 0][nf * 16 + l15] = a0[0] + a1[0];
        zsh[rr + 1][nf * 16 + l15] = a0[1] + a1[1];
        zsh[rr + 2][nf * 16 + l15] = a0[2] + a1[2];
        zsh[rr + 3][nf * 16 + l15] = a0[3] + a1[3];
      }
      __syncthreads();
      zr0 = *(const float4*)&zsh[pb][uq * 16 + 0];
      zr1 = *(const float4*)&zsh[pb][uq * 16 + 4];
      zr2 = *(const float4*)&zsh[pb][uq * 16 + 8];
      zr3 = *(const float4*)&zsh[pb][uq * 16 + 12];
    } else {
      zr0 = zr1 = zr2 = zr3 = make_float4(0.f, 0.f, 0.f, 0.f);
    }

    // gates for 4 units
    int mv = (int)((mwrd >> pb) & 1ull);
#define GATES(CC, HH, Z0, Z1, Z2, Z3, ZR)                              \
    {                                                                  \
      float zi = bf2f((unsigned short)(Z0)) + (ZR).x;                  \
      float zf = bf2f((unsigned short)(Z1)) + (ZR).y;                  \
      float zg = bf2f((unsigned short)(Z2)) + (ZR).z;                  \
      float zo = bf2f((unsigned short)(Z3)) + (ZR).w;                  \
      float ig = 1.f / (1.f + __expf(-zi));                            \
      float fg = 1.f / (1.f + __expf(-zf));                            \
      float gg = 2.f / (1.f + __expf(-2.f * zg)) - 1.f;                \
      float og = 1.f / (1.f + __expf(-zo));                            \
      float cn = fg * (CC) + ig * gg;                                  \
      float hn = og * (2.f / (1.f + __expf(-2.f * cn)) - 1.f);         \
      if (mv) { (CC) = cn; (HH) = hn; }                                \
    }
    GATES(c0, h0, zv0[0], zv0[1], zv0[2], zv0[3], zr0)
    GATES(c1, h1, zv0[4], zv0[5], zv0[6], zv0[7], zr1)
    GATES(c2, h2, zv1[0], zv1[1], zv1[2], zv1[3], zr2)
    GATES(c3, h3, zv1[4], zv1[5], zv1[6], zv1[7], zr3)
#undef GATES

    // h exchange: one 8B sc-bypass store per thread (critical path)
    unsigned short* hw = hbuf + ((size_t)(((s + 1) & 1) * 2 + dir)) * Bx * 320;
    unsigned long long hv =
        (unsigned long long)f2bf(h0) | ((unsigned long long)f2bf(h1) << 16) |
        ((unsigned long long)f2bf(h2) << 32) | ((unsigned long long)f2bf(h3) << 48);
    __hip_atomic_store((unsigned long long*)(hw + pb * 320 + u0 + uq * 4), hv,
                       __ATOMIC_RELAXED, __HIP_MEMORY_SCOPE_AGENT);

    __syncthreads();  // all waves drained their h stores before the signal
    if (tid == 0 && s < Tx - 1)
      __hip_atomic_store(&slots[slice * 16], (unsigned)(s + 1), __ATOMIC_RELEASE,
                         __HIP_MEMORY_SCOPE_AGENT);  // replay-proven ordering;
      // L2 is clean in this kernel (all stores write-through), so wbl2 is ~free.

    // out: write-through u64 pairs — full exclusive 64B line per (WG, pb) quad,
    // never dirties L2 (keeps the release cheap), off the critical path.
    union { float f[4]; unsigned long long q[2]; } ou;
    ou.f[0] = h0; ou.f[1] = h1; ou.f[2] = h2; ou.f[3] = h3;
    unsigned long long* op = (unsigned long long*)(out +
        ((size_t)pb * Tx + t) * 640 + dir * 320 + u0 + uq * 4);
    __hip_atomic_store(op, ou.q[0], __ATOMIC_RELAXED, __HIP_MEMORY_SCOPE_AGENT);
    __hip_atomic_store(op + 1, ou.q[1], __ATOMIC_RELAXED, __HIP_MEMORY_SCOPE_AGENT);
    if (s == Tx - 1) {
      unsigned long long* fp = (unsigned long long*)(out + 40960000ull +
          (size_t)pb * 640 + dir * 320 + u0 + uq * 4);
      __hip_atomic_store(fp, ou.q[0], __ATOMIC_RELAXED, __HIP_MEMORY_SCOPE_AGENT);
      __hip_atomic_store(fp + 1, ou.q[1], __ATOMIC_RELAXED, __HIP_MEMORY_SCOPE_AGENT);
      break;  // uniform
    }

    // prefetch next step's Zx slab + mask word (overlaps barrier wait)
    int tn = dir ? (Tx - 2 - s) : (s + 1);
    zv0 = *(const short8*)(zbase + (size_t)tn * 4096 + pb * 64 + uq * 16);
    zv1 = *(const short8*)(zbase + (size_t)tn * 4096 + pb * 64 + uq * 16 + 8);
    mwrd = mask2[tn];
  }
}

extern "C" void kernel_launch(void* const* d_in, const int* in_sizes, int n_in,
                              void* d_out, int out_size, void* d_ws, size_t ws_size,
                              hipStream_t stream) {
  const float* X = (const float*)d_in[0];
  const void* Mk = d_in[1];
  const float* Wf = (const float*)d_in[2];
  const float* Uf = (const float*)d_in[3];
  const float* bfv = (const float*)d_in[4];
  const float* Wb = (const float*)d_in[5];
  const float* Ub = (const float*)d_in[6];
  const float* bbv = (const float*)d_in[7];

  char* ws = (char*)d_ws;
  unsigned short* Xb = (unsigned short*)(ws + OFF_XB);
  unsigned short* Wt = (unsigned short*)(ws + OFF_WT);
  float* bp = (float*)(ws + OFF_BP);
  unsigned short* Zx = (unsigned short*)(ws + OFF_ZX);
  unsigned long long* mask2 = (unsigned long long*)(ws + OFF_MB);
  unsigned short* hbuf = (unsigned short*)(ws + OFF_HB);
  unsigned* bar = (unsigned*)(ws + OFF_BAR);

  k_prep_x<<<dim3(20000), dim3(256), 0, stream>>>(X, Xb);
  k_prep_w<<<dim3(3200), dim3(256), 0, stream>>>(Wf, Wb, bfv, bbv, Wt, bp);
  k_gemm<<<dim3(10000), dim3(256), 0, stream>>>(Xb, Wt, bp, Zx);
  // mask2/bar/hbuf overlay the (now dead) Xb region — initialize after k_gemm
  hipMemsetAsync(ws + OFF_BAR, 0, 2560, stream);
  k_prep_mask<<<dim3(4), dim3(256), 0, stream>>>(Mk, mask2);
  k_lstm<<<dim3(2 * NSLICE), dim3(256), 0, stream>>>(Zx, Uf, Ub, mask2, hbuf,
                                                     (float*)d_out, bar);
}

// Round 5
// 5298.067 us; speedup vs baseline: 2.5408x; 1.0700x over previous
//
#include <hip/hip_runtime.h>
#include <hip/hip_bf16.h>
#include <stdint.h>

// BidLSTM: B=64, T=1000, C=320, U=320.
// Phase 1: Zx[dir][slice][t][b][64] = bf16(X@W + b), slice = 16-unit group, via MFMA GEMM.
// Phase 2: persistent kernel, 40 WGs (20/dir, 16 units each), U-slice in registers.
//          NO barrier: data-as-signal h exchange. h words (packed 4xbf16 u64) are
//          written once per ring slot; consumers poll for != SENTINEL. 4-deep ring;
//          slot (s+2)&3 is reset at step s (visibility transitively ordered by the
//          vmcnt(0) drain of the zsh __syncthreads before the next h store).

#define Bx 64
#define Tx 1000
#define Cx 320
#define NSLICE 20   // WGs per direction
#define UPW 16      // units per WG
#define SENT 0xFFFFFFFFFFFFFFFFull

typedef __attribute__((ext_vector_type(8))) short short8;
typedef __attribute__((ext_vector_type(4))) short short4v;
typedef __attribute__((ext_vector_type(4))) float f32x4;

__device__ inline unsigned short f2bf(float f) {
  unsigned x = __builtin_bit_cast(unsigned, f);
  x += 0x7fffu + ((x >> 16) & 1u);
  return (unsigned short)(x >> 16);
}
__device__ inline float bf2f(unsigned short u) {
  unsigned x = ((unsigned)u) << 16;
  return __builtin_bit_cast(float, x);
}

// ---- ws layout (bytes) ----
// Xb region [0, 40.96 MB) is dead after k_gemm; mask2/hring overlay it.
#define OFF_MB   0ull                 // mask2 [1000] u64 = 8,000
#define OFF_HB   16384ull             // hring [4slot][2dir][64][320] bf16 = 327,680
#define OFF_XB   0ull                 // Xb [64000][320] bf16 = 40,960,000 (pre-GEMM only)
#define OFF_WT   40960000ull          // Wt [2][1280][320] bf16 = 1,638,400
#define OFF_BP   42598400ull          // bias [2][1280] f32 = 10,240
#define OFF_ZX   42608640ull          // Zx [2][20][1000][4096] bf16 = 327,680,000
// total = 370,288,640 (same footprint as rounds 1-4 — proven to fit)

// Convert X [b][t][c] f32 -> Xb [(t*64+b)][c] bf16
__global__ __launch_bounds__(256) void k_prep_x(const float* __restrict__ X,
                                                unsigned short* __restrict__ Xb) {
  int i4 = blockIdx.x * 256 + threadIdx.x;
  if (i4 >= Bx * Tx * Cx / 4) return;
  int idx = i4 * 4;
  int b = idx / (Tx * Cx);
  int rem = idx - b * (Tx * Cx);
  int t = rem / Cx;
  int c = rem - t * Cx;
  float4 v = *(const float4*)(X + idx);
  short4v o;
  o[0] = (short)f2bf(v.x); o[1] = (short)f2bf(v.y);
  o[2] = (short)f2bf(v.z); o[3] = (short)f2bf(v.w);
  *(short4v*)(Xb + (size_t)(t * Bx + b) * Cx + c) = o;
}

// Wt[dir][n'][k] = bf16(W[dir][k][g*320+u]) where n' = u*4+g; biasp[dir][n'] likewise
__global__ __launch_bounds__(256) void k_prep_w(const float* __restrict__ Wf,
                                                const float* __restrict__ Wb,
                                                const float* __restrict__ bfv,
                                                const float* __restrict__ bbv,
                                                unsigned short* __restrict__ Wt,
                                                float* __restrict__ biasp) {
  int gid = blockIdx.x * 256 + threadIdx.x;
  if (gid < 2 * 1280 * 320) {
    int dir = gid / (1280 * 320);
    int rem = gid - dir * 1280 * 320;
    int n = rem / 320;
    int k = rem - n * 320;
    int u = n >> 2, g = n & 3;
    const float* W = dir ? Wb : Wf;
    Wt[gid] = f2bf(W[k * 1280 + g * 320 + u]);
  }
  if (gid < 2 * 1280) {
    int dir = gid / 1280, n = gid - dir * 1280;
    int u = n >> 2, g = n & 3;
    const float* bsrc = dir ? bbv : bfv;
    biasp[gid] = bsrc[g * 320 + u];
  }
}

// mask2[t] = bitmask over batches (bit b = mask[b][t]); detects byte vs int32 mask.
__global__ __launch_bounds__(256) void k_prep_mask(const void* __restrict__ maskp,
                                                   unsigned long long* __restrict__ mask2) {
  int t = blockIdx.x * 256 + threadIdx.x;
  if (t >= Tx) return;
  const unsigned* mw = (const unsigned*)maskp;
  const bool mbyte = (mw[0] == 0x01010101u);
  unsigned long long wv = 0ull;
  if (mbyte) {
    const unsigned char* m8 = (const unsigned char*)maskp;
#pragma unroll 8
    for (int b = 0; b < Bx; b++)
      wv |= (unsigned long long)(m8[b * Tx + t] & 1) << b;
  } else {
    const int* m32 = (const int*)maskp;
#pragma unroll 8
    for (int b = 0; b < Bx; b++)
      wv |= (unsigned long long)(m32[b * Tx + t] & 1) << b;
  }
  mask2[t] = wv;
}

// C = A @ Bt^T + bias, written to Zx[dir][slice][t][b][64]. 128x128 tile, BK=64.
__global__ __launch_bounds__(256) void k_gemm(const unsigned short* __restrict__ A,
                                              const unsigned short* __restrict__ Bt,
                                              const float* __restrict__ biasp,
                                              unsigned short* __restrict__ Czx) {
  int bid = blockIdx.x;
  int dir = bid / 5000;
  int r = bid - dir * 5000;
  int tm = r / 10, tn = r - (r / 10) * 10;
  long m0 = (long)tm * 128;
  int n0 = tn * 128;
  const unsigned short* Bd = Bt + (size_t)dir * 1280 * 320;
  const float* bias = biasp + dir * 1280;

  __shared__ __align__(16) unsigned short As[128 * 64];
  __shared__ __align__(16) unsigned short Bs[128 * 64];

  int tid = threadIdx.x;
  int wave = tid >> 6, lane = tid & 63;
  int l15 = lane & 15, l4 = lane >> 4;

  f32x4 acc[2][8];
#pragma unroll
  for (int i = 0; i < 2; i++)
#pragma unroll
    for (int j = 0; j < 8; j++) acc[i][j] = (f32x4){0.f, 0.f, 0.f, 0.f};

  for (int k0 = 0; k0 < 320; k0 += 64) {
    __syncthreads();
#pragma unroll
    for (int it = 0; it < 4; it++) {
      int idx = it * 256 + tid;
      int rr = idx >> 3, cc = idx & 7;
      const unsigned short* ga = A + (size_t)(m0 + rr) * 320 + k0 + cc * 8;
      unsigned short* la = As + (size_t)(it * 256 + wave * 64) * 8;
      __builtin_amdgcn_global_load_lds(
          (const __attribute__((address_space(1))) void*)ga,
          (__attribute__((address_space(3))) void*)la, 16, 0, 0);
      const unsigned short* gb = Bd + (size_t)(n0 + rr) * 320 + k0 + cc * 8;
      unsigned short* lb = Bs + (size_t)(it * 256 + wave * 64) * 8;
      __builtin_amdgcn_global_load_lds(
          (const __attribute__((address_space(1))) void*)gb,
          (__attribute__((address_space(3))) void*)lb, 16, 0, 0);
    }
    __syncthreads();
#pragma unroll
    for (int kk = 0; kk < 2; kk++) {
      short8 af[2], bf8[8];
#pragma unroll
      for (int mf = 0; mf < 2; mf++)
        af[mf] = *(const short8*)(As + (wave * 32 + mf * 16 + l15) * 64 + kk * 32 + l4 * 8);
#pragma unroll
      for (int nf = 0; nf < 8; nf++)
        bf8[nf] = *(const short8*)(Bs + (nf * 16 + l15) * 64 + kk * 32 + l4 * 8);
#pragma unroll
      for (int mf = 0; mf < 2; mf++)
#pragma unroll
        for (int nf = 0; nf < 8; nf++)
          acc[mf][nf] = __builtin_amdgcn_mfma_f32_16x16x32_bf16(af[mf], bf8[nf], acc[mf][nf], 0, 0, 0);
    }
  }
  // epilogue: Zx element = ((dir*20+slice)*1000 + t)*4096 + b*64 + i64
#pragma unroll
  for (int mf = 0; mf < 2; mf++) {
#pragma unroll
    for (int nf = 0; nf < 8; nf++) {
      int col = n0 + nf * 16 + l15;
      float bv = bias[col];
      int slice = col >> 6, i64v = col & 63;
      size_t sbase = ((size_t)(dir * NSLICE + slice)) * Tx * 4096;
#pragma unroll
      for (int i = 0; i < 4; i++) {
        long m = m0 + wave * 32 + mf * 16 + l4 * 4 + i;
        long t = m >> 6;
        int b = (int)(m & 63);
        Czx[sbase + (size_t)t * 4096 + b * 64 + i64v] = f2bf(acc[mf][nf][i] + bv);
      }
    }
  }
}

// Persistent recurrent kernel. 40 WGs x 256 threads. WG = (dir, 16-unit slice).
__global__ __launch_bounds__(256, 1) void k_lstm(const unsigned short* __restrict__ Zx,
                                                 const float* __restrict__ Uf,
                                                 const float* __restrict__ Ub,
                                                 const unsigned long long* __restrict__ mask2,
                                                 unsigned short* __restrict__ hring,
                                                 float* __restrict__ out) {
  const int w = blockIdx.x;
  const int dir = w / NSLICE;
  const int slice = w - dir * NSLICE;
  const int u0 = slice * UPW;
  const int tid = threadIdx.x;
  const int wave = tid >> 6, lane = tid & 63;
  const int l15 = lane & 15, l4 = lane >> 4;

  // U slice as MFMA B-fragments in registers, resident for all 1000 steps.
  const float* U = dir ? Ub : Uf;
  short8 bfrag[4][10];
#pragma unroll
  for (int nf = 0; nf < 4; nf++) {
    int ncol = nf * 16 + l15;                       // col within 64-wide slice
    int colU = (ncol & 3) * 320 + u0 + (ncol >> 2); // original U column
#pragma unroll
    for (int kt = 0; kt < 10; kt++) {
      short8 v;
#pragma unroll
      for (int j = 0; j < 8; j++)
        v[j] = (short)f2bf(U[(size_t)(kt * 32 + l4 * 8 + j) * 1280 + colU]);
      bfrag[nf][kt] = v;
    }
  }

  // pointwise mapping: thread = (batch pb, unit quad uq -> units u0+uq*4 .. +3)
  const int pb = tid >> 2;
  const int uq = tid & 3;
  const int arow = wave * 16 + l15;  // batch row for A-fragment (poll row)
  float c0 = 0.f, c1 = 0.f, c2 = 0.f, c3 = 0.f;
  float h0 = 0.f, h1 = 0.f, h2 = 0.f, h3 = 0.f;

  __shared__ float zsh[64][68];  // padded: 272B row stride, 16B aligned

  const unsigned short* zbase = Zx + ((size_t)(dir * NSLICE + slice)) * Tx * 4096;
  // ring slot base (elements): HR(slot) = hring + (slot*2 + dir)*64*320
#define HR(SL) (hring + ((size_t)((SL) * 2 + dir)) * Bx * 320)

  // prefetch step 0
  int t = dir ? (Tx - 1) : 0;
  short8 zv0 = *(const short8*)(zbase + (size_t)t * 4096 + pb * 64 + uq * 16);
  short8 zv1 = *(const short8*)(zbase + (size_t)t * 4096 + pb * 64 + uq * 16 + 8);
  unsigned long long mwrd = mask2[t];

  unsigned long long q[20];          // in-flight poll values (h row arow)
  const unsigned long long* pollp = nullptr;

  for (int s = 0;; ++s) {
    t = dir ? (Tx - 1 - s) : s;
    float4 zr0, zr1, zr2, zr3;
    if (s > 0) {
      // complete the poll issued at the end of step s-1: all 20 words != SENT
      for (;;) {
        bool any = false;
#pragma unroll
        for (int i = 0; i < 20; i++) any |= (q[i] == SENT);
        if (!any) break;
#pragma unroll
        for (int i = 0; i < 20; i++)
          if (q[i] == SENT)
            q[i] = __hip_atomic_load(pollp + (i >> 1) * 8 + (i & 1),
                                     __ATOMIC_RELAXED, __HIP_MEMORY_SCOPE_AGENT);
      }
      // h @ U_slice via MFMA (A-fragments from polled words)
      short8 afr[10];
#pragma unroll
      for (int kt = 0; kt < 10; kt++) {
        union { unsigned long long qq[2]; short8 v; } u;
        u.qq[0] = q[2 * kt];
        u.qq[1] = q[2 * kt + 1];
        afr[kt] = u.v;
      }
#pragma unroll
      for (int nf = 0; nf < 4; nf++) {
        f32x4 a0 = {0.f, 0.f, 0.f, 0.f}, a1 = {0.f, 0.f, 0.f, 0.f};
#pragma unroll
        for (int k2 = 0; k2 < 5; k2++) {
          a0 = __builtin_amdgcn_mfma_f32_16x16x32_bf16(afr[2 * k2], bfrag[nf][2 * k2], a0, 0, 0, 0);
          a1 = __builtin_amdgcn_mfma_f32_16x16x32_bf16(afr[2 * k2 + 1], bfrag[nf][2 * k2 + 1], a1, 0, 0, 0);
        }
        int rr = wave * 16 + l4 * 4;
        zsh[rr + 0][nf * 16 + l15] = a0[0] + a1[0];
        zsh[rr + 1][nf * 16 + l15] = a0[1] + a1[1];
        zsh[rr + 2][nf * 16 + l15] = a0[2] + a1[2];
        zsh[rr + 3][nf * 16 + l15] = a0[3] + a1[3];
      }
      __syncthreads();  // vmcnt(0) drain: also publishes step s-1's slot resets
      zr0 = *(const float4*)&zsh[pb][uq * 16 + 0];
      zr1 = *(const float4*)&zsh[pb][uq * 16 + 4];
      zr2 = *(const float4*)&zsh[pb][uq * 16 + 8];
      zr3 = *(const float4*)&zsh[pb][uq * 16 + 12];
    } else {
      zr0 = zr1 = zr2 = zr3 = make_float4(0.f, 0.f, 0.f, 0.f);
    }

    // gates for 4 units
    int mv = (int)((mwrd >> pb) & 1ull);
#define GATES(CC, HH, Z0, Z1, Z2, Z3, ZR)                              \
    {                                                                  \
      float zi = bf2f((unsigned short)(Z0)) + (ZR).x;                  \
      float zf = bf2f((unsigned short)(Z1)) + (ZR).y;                  \
      float zg = bf2f((unsigned short)(Z2)) + (ZR).z;                  \
      float zo = bf2f((unsigned short)(Z3)) + (ZR).w;                  \
      float ig = 1.f / (1.f + __expf(-zi));                            \
      float fg = 1.f / (1.f + __expf(-zf));                            \
      float gg = 2.f / (1.f + __expf(-2.f * zg)) - 1.f;                \
      float og = 1.f / (1.f + __expf(-zo));                            \
      float cn = fg * (CC) + ig * gg;                                  \
      float hn = og * (2.f / (1.f + __expf(-2.f * cn)) - 1.f);         \
      if (mv) { (CC) = cn; (HH) = hn; }                                \
    }
    GATES(c0, h0, zv0[0], zv0[1], zv0[2], zv0[3], zr0)
    GATES(c1, h1, zv0[4], zv0[5], zv0[6], zv0[7], zr1)
    GATES(c2, h2, zv1[0], zv1[1], zv1[2], zv1[3], zr2)
    GATES(c3, h3, zv1[4], zv1[5], zv1[6], zv1[7], zr3)
#undef GATES

    union { float f[4]; unsigned long long qq[2]; } ou;
    ou.f[0] = h0; ou.f[1] = h1; ou.f[2] = h2; ou.f[3] = h3;

    if (s < Tx - 1) {
      // h publish: the data IS the signal (write-once into slot s&3)
      unsigned long long hv =
          (unsigned long long)f2bf(h0) | ((unsigned long long)f2bf(h1) << 16) |
          ((unsigned long long)f2bf(h2) << 32) | ((unsigned long long)f2bf(h3) << 48);
      __hip_atomic_store((unsigned long long*)(HR(s & 3) + pb * 320 + u0 + uq * 4),
                         hv, __ATOMIC_RELAXED, __HIP_MEMORY_SCOPE_AGENT);
    }

    // out: write-through u64 pairs (full exclusive 64B line per (WG, pb) quad)
    unsigned long long* op = (unsigned long long*)(out +
        ((size_t)pb * Tx + t) * 640 + dir * 320 + u0 + uq * 4);
    __hip_atomic_store(op, ou.qq[0], __ATOMIC_RELAXED, __HIP_MEMORY_SCOPE_AGENT);
    __hip_atomic_store(op + 1, ou.qq[1], __ATOMIC_RELAXED, __HIP_MEMORY_SCOPE_AGENT);
    if (s == Tx - 1) {
      unsigned long long* fp = (unsigned long long*)(out + 40960000ull +
          (size_t)pb * 640 + dir * 320 + u0 + uq * 4);
      __hip_atomic_store(fp, ou.qq[0], __ATOMIC_RELAXED, __HIP_MEMORY_SCOPE_AGENT);
      __hip_atomic_store(fp + 1, ou.qq[1], __ATOMIC_RELAXED, __HIP_MEMORY_SCOPE_AGENT);
      break;  // uniform
    }

    // reset slot (s+2)&3 (holds h^{s-2}; all consumers provably done). Visibility
    // is ordered by the next step's zsh __syncthreads (vmcnt(0)) before h^{s+1}.
    __hip_atomic_store((unsigned long long*)(HR((s + 2) & 3) + pb * 320 + u0 + uq * 4),
                       SENT, __ATOMIC_RELAXED, __HIP_MEMORY_SCOPE_AGENT);

    // prefetch next step's Zx slab + mask word
    int tn = dir ? (Tx - 2 - s) : (s + 1);
    zv0 = *(const short8*)(zbase + (size_t)tn * 4096 + pb * 64 + uq * 16);
    zv1 = *(const short8*)(zbase + (size_t)tn * 4096 + pb * 64 + uq * 16 + 8);
    mwrd = mask2[tn];

    // issue next poll round (slot s&3, row arow) — hides one MALL RT
    pollp = (const unsigned long long*)(HR(s & 3) + arow * 320 + l4 * 8);
#pragma unroll
    for (int i = 0; i < 20; i++)
      q[i] = __hip_atomic_load(pollp + (i >> 1) * 8 + (i & 1),
                               __ATOMIC_RELAXED, __HIP_MEMORY_SCOPE_AGENT);
  }
#undef HR
}

extern "C" void kernel_launch(void* const* d_in, const int* in_sizes, int n_in,
                              void* d_out, int out_size, void* d_ws, size_t ws_size,
                              hipStream_t stream) {
  const float* X = (const float*)d_in[0];
  const void* Mk = d_in[1];
  const float* Wf = (const float*)d_in[2];
  const float* Uf = (const float*)d_in[3];
  const float* bfv = (const float*)d_in[4];
  const float* Wb = (const float*)d_in[5];
  const float* Ub = (const float*)d_in[6];
  const float* bbv = (const float*)d_in[7];

  char* ws = (char*)d_ws;
  unsigned short* Xb = (unsigned short*)(ws + OFF_XB);
  unsigned short* Wt = (unsigned short*)(ws + OFF_WT);
  float* bp = (float*)(ws + OFF_BP);
  unsigned short* Zx = (unsigned short*)(ws + OFF_ZX);
  unsigned long long* mask2 = (unsigned long long*)(ws + OFF_MB);
  unsigned short* hring = (unsigned short*)(ws + OFF_HB);

  k_prep_x<<<dim3(20000), dim3(256), 0, stream>>>(X, Xb);
  k_prep_w<<<dim3(3200), dim3(256), 0, stream>>>(Wf, Wb, bfv, bbv, Wt, bp);
  k_gemm<<<dim3(10000), dim3(256), 0, stream>>>(Xb, Wt, bp, Zx);
  // mask2/hring overlay the (now dead) Xb region — initialize after k_gemm
  hipMemsetAsync(ws + OFF_HB, 0xFF, 327680, stream);  // hring = all-sentinel
  k_prep_mask<<<dim3(4), dim3(256), 0, stream>>>(Mk, mask2);
  k_lstm<<<dim3(2 * NSLICE), dim3(256), 0, stream>>>(Zx, Uf, Ub, mask2, hring,
                                                     (float*)d_out);
}